// Round 6
// baseline (12890.324 us; speedup 1.0000x reference)
//
#include <hip/hip_runtime.h>
#include <math.h>

#define T_STEPS 4096
#define HID     1024
#define G4      4096   // 4*HID gate rows
#define NB      64     // recurrence blocks (one per CU, all co-resident)

// ---- tagged-word publish: one 64-bit atomic = {u32 step-tag | f32 value} ----
__device__ __forceinline__ unsigned long long ld64(const unsigned long long* p) {
    return __hip_atomic_load(p, __ATOMIC_RELAXED, __HIP_MEMORY_SCOPE_AGENT);
}
__device__ __forceinline__ void st64(unsigned long long* p, unsigned long long v) {
    __hip_atomic_store(p, v, __ATOMIC_RELAXED, __HIP_MEMORY_SCOPE_AGENT);
}
__device__ __forceinline__ unsigned long long packhv(float h, unsigned tag) {
    return ((unsigned long long)tag << 32) | (unsigned long long)__float_as_uint(h);
}
__device__ __forceinline__ float fsigmoid(float x) {
    return __fdividef(1.0f, 1.0f + __expf(-x));
}
__device__ __forceinline__ float ftanh(float x) {
    // tanh(x) = 2/(1+e^{-2x}) - 1
    return __fdividef(2.0f, 1.0f + __expf(-2.0f * x)) - 1.0f;
}

// ---------------------------------------------------------------------------
// Kernel 1: xg[t][r] = dot(x[t,:], w_ih[r,:]) + b_ih[r] + b_hh[r]
// f32 GEMM, 64x64 tile, K-chunk 32, 256 threads, 4x4 per thread.
// Blocks (0, y<8) also zero h_pub (2x1024 u64) so each graph replay resets.
// ---------------------------------------------------------------------------
__global__ __launch_bounds__(256) void xg_gemm(
    const float* __restrict__ x, const float* __restrict__ w_ih,
    const float* __restrict__ b_ih, const float* __restrict__ b_hh,
    float* __restrict__ xg, unsigned long long* __restrict__ h_pub)
{
    if (blockIdx.x == 0 && blockIdx.y < 8)
        h_pub[blockIdx.y * 256 + threadIdx.x] = 0ull;

    __shared__ float Xs[32][68];   // [k][m], pad kills conflicts
    __shared__ float Ws[32][68];   // [k][n]

    const int t0  = blockIdx.y * 64;
    const int n0  = blockIdx.x * 64;
    const int thr = threadIdx.x;
    const int tx  = thr & 15;      // n-group
    const int ty  = thr >> 4;      // m-group

    float acc[4][4] = {};

    for (int kk = 0; kk < 1024; kk += 32) {
        #pragma unroll
        for (int i = 0; i < 2; i++) {
            int flat = thr + i * 256;       // 0..511
            int m    = flat >> 3;           // 0..63
            int kc   = flat & 7;            // k-chunk (4 floats)
            float4 xv = *(const float4*)(x    + (size_t)(t0 + m) * 1024 + kk + kc * 4);
            float4 wv = *(const float4*)(w_ih + (size_t)(n0 + m) * 1024 + kk + kc * 4);
            Xs[kc*4+0][m] = xv.x; Xs[kc*4+1][m] = xv.y;
            Xs[kc*4+2][m] = xv.z; Xs[kc*4+3][m] = xv.w;
            Ws[kc*4+0][m] = wv.x; Ws[kc*4+1][m] = wv.y;
            Ws[kc*4+2][m] = wv.z; Ws[kc*4+3][m] = wv.w;
        }
        __syncthreads();
        #pragma unroll
        for (int k = 0; k < 32; k++) {
            float4 a4 = *(const float4*)&Xs[k][ty * 4];
            float4 b4 = *(const float4*)&Ws[k][tx * 4];
            float av[4] = {a4.x, a4.y, a4.z, a4.w};
            float bv[4] = {b4.x, b4.y, b4.z, b4.w};
            #pragma unroll
            for (int i = 0; i < 4; i++)
                #pragma unroll
                for (int j = 0; j < 4; j++)
                    acc[i][j] = fmaf(av[i], bv[j], acc[i][j]);
        }
        __syncthreads();
    }

    float4 bi = *(const float4*)(b_ih + n0 + tx * 4);
    float4 bh = *(const float4*)(b_hh + n0 + tx * 4);
    float bb[4] = {bi.x + bh.x, bi.y + bh.y, bi.z + bh.z, bi.w + bh.w};
    #pragma unroll
    for (int i = 0; i < 4; i++) {
        float4 o;
        o.x = acc[i][0] + bb[0]; o.y = acc[i][1] + bb[1];
        o.z = acc[i][2] + bb[2]; o.w = acc[i][3] + bb[3];
        *(float4*)(xg + (size_t)(t0 + ty * 4 + i) * G4 + n0 + tx * 4) = o;
    }
}

// ---------------------------------------------------------------------------
// Kernel 2: persistent recurrence. 64 blocks x 512 threads, 1 block/CU
// (__launch_bounds__(512,2) -> 256-VGPR cap so 128 weight floats stay
// resident; weights are opacified with scalar empty-asm so they can't be
// rematerialized).
// Block b owns hidden units [b*16, b*16+16). Wave rg owns 2 units
// (b*16+2*rg, +1) x 4 gates = 8 rows: rr -> row (rr&3)*HID + b*16 + 2*rg
// + (rr>>2). Lane ec owns cols [16ec, 16ec+16).
// Per step: poll own 2 tagged words -> stage to h_lds[parity] -> barrier ->
// 8x16 dot -> 10-shuffle fold (lane holds row ec&7) -> +xg -> 3-shuffle
// gather -> gates on lanes 0/4 -> fire-and-forget tagged publish.
// ONE barrier per step, no fences.
// ---------------------------------------------------------------------------
__global__ __launch_bounds__(512, 2) void lstm_rec(
    const float* __restrict__ xg, const float* __restrict__ w_hh,
    const float* __restrict__ h0, const float* __restrict__ c0,
    const float* __restrict__ w_out, const float* __restrict__ b_out,
    unsigned long long* __restrict__ h_pub,   // [2][HID] tagged words
    float* __restrict__ out)
{
    __shared__ float h_lds[2][64 * 20];   // double-buffered, stride-20 chunks
    __shared__ float red_lds[8];

    const int thr = threadIdx.x;
    const int b   = blockIdx.x;
    const int rg  = thr >> 6;          // wave 0..7
    const int ec  = thr & 63;          // lane 0..63

    // this wave's 8 rows: gate = rr&3, unit-delta = rr>>2
    int grow[8];
    #pragma unroll
    for (int rr = 0; rr < 8; rr++)
        grow[rr] = (rr & 3) * HID + b * 16 + 2 * rg + (rr >> 2);

    // ---- preload weights into scalar regs: w[rr][j] = w_hh[grow[rr]][16ec+j]
    float w[8][16];
    #pragma unroll
    for (int rr = 0; rr < 8; rr++) {
        const float* wr = w_hh + (size_t)grow[rr] * HID + ec * 16;
        #pragma unroll
        for (int q = 0; q < 4; q++) {
            float4 v = *(const float4*)(wr + q * 4);
            w[rr][q*4+0] = v.x; w[rr][q*4+1] = v.y;
            w[rr][q*4+2] = v.z; w[rr][q*4+3] = v.w;
        }
    }
    // opacify (scalar operands only): prevent rematerialization in the loop
    #pragma unroll
    for (int rr = 0; rr < 8; rr++)
        asm volatile("" :
            "+v"(w[rr][0]),  "+v"(w[rr][1]),  "+v"(w[rr][2]),  "+v"(w[rr][3]),
            "+v"(w[rr][4]),  "+v"(w[rr][5]),  "+v"(w[rr][6]),  "+v"(w[rr][7]),
            "+v"(w[rr][8]),  "+v"(w[rr][9]),  "+v"(w[rr][10]), "+v"(w[rr][11]),
            "+v"(w[rr][12]), "+v"(w[rr][13]), "+v"(w[rr][14]), "+v"(w[rr][15]));

    // ---- init: c lives on lanes 0 and 4 of each wave (unit b*16+2rg+(ec>>2))
    const int myunit = b * 16 + 2 * rg + (ec >> 2);   // valid on lanes 0,4
    float c = 0.0f;
    if (ec == 0 || ec == 4) {
        c = c0[myunit];
        st64(&h_pub[0 * HID + myunit], packhv(h0[myunit], 1u));
    }

    const int u0 = 2 * thr;            // this thread's two staged h units
    const int l0 = (u0 >> 4) * 20 + (u0 & 15);
    const int xrow = grow[ec & 7];     // xg row whose total this lane will hold

    for (int t = 0; t < T_STEPS; t++) {
        const int p = t & 1;

        // xg prefetch (independent of the handoff)
        float xgv = xg[(size_t)t * G4 + xrow];

        // ---- spin on own two tagged words
        const unsigned tag = (unsigned)(t + 1);
        const unsigned long long* a0 = &h_pub[p * HID + u0];
        unsigned long long v0 = ld64(a0), v1 = ld64(a0 + 1);
        while (((unsigned)(v0 >> 32) != tag) | ((unsigned)(v1 >> 32) != tag)) {
            v0 = ld64(a0); v1 = ld64(a0 + 1);
        }
        h_lds[p][l0]     = __uint_as_float((unsigned)v0);
        h_lds[p][l0 + 1] = __uint_as_float((unsigned)v1);
        __syncthreads();

        // ---- dot: 8 rows x 16 elems per thread
        float4 h4[4];
        #pragma unroll
        for (int q = 0; q < 4; q++)
            h4[q] = *(const float4*)&h_lds[p][ec * 20 + q * 4];
        float hx[16] = {h4[0].x,h4[0].y,h4[0].z,h4[0].w,
                        h4[1].x,h4[1].y,h4[1].z,h4[1].w,
                        h4[2].x,h4[2].y,h4[2].z,h4[2].w,
                        h4[3].x,h4[3].y,h4[3].z,h4[3].w};

        float a[8];
        #pragma unroll
        for (int rr = 0; rr < 8; rr++) {
            float s0 = 0.f, s1 = 0.f, s2 = 0.f, s3 = 0.f;
            #pragma unroll
            for (int q = 0; q < 4; q++) {
                s0 = fmaf(w[rr][q*4+0], hx[q*4+0], s0);
                s1 = fmaf(w[rr][q*4+1], hx[q*4+1], s1);
                s2 = fmaf(w[rr][q*4+2], hx[q*4+2], s2);
                s3 = fmaf(w[rr][q*4+3], hx[q*4+3], s3);
            }
            a[rr] = (s0 + s1) + (s2 + s3);
        }

        // ---- multi-value fold: 8 accs x 64 lanes -> lane ec holds row ec&7
        const bool b0 = (ec & 1), b1 = (ec & 2), b2 = (ec & 4);
        float f[4];
        #pragma unroll
        for (int i = 0; i < 4; i++) {
            float send = b0 ? a[2*i] : a[2*i+1];
            float recv = __shfl_xor(send, 1, 64);
            f[i] = (b0 ? a[2*i+1] : a[2*i]) + recv;
        }
        float g2[2];
        #pragma unroll
        for (int i = 0; i < 2; i++) {
            float send = b1 ? f[2*i] : f[2*i+1];
            float recv = __shfl_xor(send, 2, 64);
            g2[i] = (b1 ? f[2*i+1] : f[2*i]) + recv;
        }
        float d;
        {
            float send = b2 ? g2[0] : g2[1];
            float recv = __shfl_xor(send, 4, 64);
            d = (b2 ? g2[1] : g2[0]) + recv;
        }
        d += __shfl_xor(d, 8, 64);
        d += __shfl_xor(d, 16, 64);
        d += __shfl_xor(d, 32, 64);
        d += xgv;                       // full preact for row grow[ec&7]

        // ---- gather {i,f,g,o} onto lanes 0 (unit 2rg) and 4 (unit 2rg+1)
        float v1g = __shfl_xor(d, 1, 64);   // row (ec^1)&7
        float v2g = __shfl_xor(d, 2, 64);   // row (ec^2)&7
        float v3g = __shfl_xor(d, 3, 64);   // row (ec^3)&7

        if (ec == 0 || ec == 4) {
            float si = fsigmoid(d);         // gate i  (rr&3 == 0)
            float sf = fsigmoid(v1g);       // gate f
            float tg = ftanh(v2g);          // gate g
            float so = fsigmoid(v3g);       // gate o
            c = sf * c + si * tg;
            float hn = so * ftanh(c);
            st64(&h_pub[(p ^ 1) * HID + myunit], packhv(hn, (unsigned)(t + 2)));
        }
    }

    // ---- tail: block 0 computes pred = tanh(w_out . h_final + b_out)
    if (b == 0) {
        const unsigned tag = (unsigned)(T_STEPS + 1);    // final h in buffer 0
        const unsigned long long* a0 = &h_pub[0 * HID + u0];
        unsigned long long v0 = ld64(a0), v1 = ld64(a0 + 1);
        while (((unsigned)(v0 >> 32) != tag) | ((unsigned)(v1 >> 32) != tag)) {
            v0 = ld64(a0); v1 = ld64(a0 + 1);
        }
        float part = __uint_as_float((unsigned)v0) * w_out[u0]
                   + __uint_as_float((unsigned)v1) * w_out[u0 + 1];
        #pragma unroll
        for (int m = 1; m < 64; m <<= 1)
            part += __shfl_xor(part, m, 64);
        __syncthreads();
        if (ec == 0) red_lds[rg] = part;
        __syncthreads();
        if (thr == 0) {
            float s = 0.f;
            #pragma unroll
            for (int i = 0; i < 8; i++) s += red_lds[i];
            out[0] = tanhf(s + b_out[0]);
        }
    }
}

// ---------------------------------------------------------------------------
extern "C" void kernel_launch(void* const* d_in, const int* in_sizes, int n_in,
                              void* d_out, int out_size, void* d_ws, size_t ws_size,
                              hipStream_t stream) {
    const float* x     = (const float*)d_in[0];
    const float* h0    = (const float*)d_in[1];
    const float* c0    = (const float*)d_in[2];
    const float* w_ih  = (const float*)d_in[3];
    const float* w_hh  = (const float*)d_in[4];
    const float* b_ih  = (const float*)d_in[5];
    const float* b_hh  = (const float*)d_in[6];
    const float* w_out = (const float*)d_in[7];
    const float* b_out = (const float*)d_in[8];
    float* out = (float*)d_out;

    char* ws = (char*)d_ws;
    float*              xg    = (float*)ws;                               // 64 MiB
    unsigned long long* h_pub = (unsigned long long*)(ws + (size_t)T_STEPS * G4 * 4);  // 16 KiB

    xg_gemm<<<dim3(64, 64), 256, 0, stream>>>(x, w_ih, b_ih, b_hh, xg, h_pub);
    lstm_rec<<<NB, 512, 0, stream>>>(xg, w_hh, h0, c0, w_out, b_out, h_pub, out);
}